// Round 12
// baseline (602.024 us; speedup 1.0000x reference)
//
#include <hip/hip_runtime.h>
#include <math.h>

typedef _Float16 half8 __attribute__((ext_vector_type(8)));
typedef _Float16 half4v __attribute__((ext_vector_type(4)));
typedef float floatx4 __attribute__((ext_vector_type(4)));

#define SQ3 1.7320508075688772f

// bw layout: [path(4)][t(8)][s(2)][lane(64)][elem(8)] _Float16  (32768 = 64 KiB)
// bw value = W2[k][col] * scale, k = s*32 + (lane>>4)*8 + elem,
// col = path*128 + t*16 + (lane&15), scale = 1/32 (sqrt3 folded into path C)
__global__ __launch_bounds__(256) void prep_w2(const float* __restrict__ W2,
                                               _Float16* __restrict__ bw) {
    int t = blockIdx.x * 256 + threadIdx.x;
    if (t >= 32768) return;
    int i    = t & 7;
    int l    = (t >> 3) & 63;
    int s    = (t >> 9) & 1;
    int tt   = (t >> 10) & 7;
    int path = t >> 13;
    int k   = s * 32 + (l >> 4) * 8 + i;
    int col = path * 128 + tt * 16 + (l & 15);
    float scale = 0.03125f * (path == 2 ? SQ3 : 1.0f);
    bw[t] = (_Float16)(W2[k * 512 + col] * scale);
}

// 512 threads = 8 waves; each wave owns one 16-edge tile end-to-end.
// Zero intra-loop barriers: LDS feature slices are wave-private.
__global__ __launch_bounds__(512, 4) void edge_kernel(
    const float* __restrict__ x, const float* __restrict__ pos,
    const int* __restrict__ ei, const float* __restrict__ W1,
    const _Float16* __restrict__ bwg, float* __restrict__ out,
    int E, int ntiles)
{
    __shared__ __align__(16) _Float16 s_bw[32768];       // 64 KiB weights
    __shared__ float sW1[64];
    __shared__ __align__(16) _Float16 s_feat[8][16][40]; // per-wave: xs(8) xv(24) dir+len(4)
    __shared__ int s_dsti[8][16];

    const int tid  = threadIdx.x;
    const int wave = tid >> 6;
    const int lane = tid & 63;
    const int e16  = lane & 15;
    const int kg   = lane >> 4;

    // one-time: weights + W1 into LDS (the only barrier in the kernel)
    {
        const half8* src = (const half8*)bwg;
        half8* dst = (half8*)s_bw;
        #pragma unroll
        for (int j = 0; j < 8; ++j)
            dst[tid * 8 + j] = src[tid * 8 + j];
        if (tid < 64) sW1[tid] = W1[tid];
    }
    __syncthreads();

    const half8* bwv = (const half8*)s_bw;
    _Float16* myfeat = &s_feat[wave][0][0];   // [16][40]
    int* mydst = &s_dsti[wave][0];

    const int wgid = blockIdx.x * 8 + wave;
    const int wnum = gridDim.x * 8;

    for (int tile = wgid; tile < ntiles; tile += wnum) {
        // ===== phase L: gather (per-lane, no barrier) =====
        int eg = tile * 16 + e16;
        int ec = (eg < E) ? eg : (E - 1);
        int si = ei[ec];
        int di = ei[E + ec];
        const float* ps = pos + (size_t)si * 3;
        const float* pd = pos + (size_t)di * 3;
        float ex = pd[0] - ps[0], ey = pd[1] - ps[1], ez = pd[2] - ps[2];
        float len = fmaxf(sqrtf(ex * ex + ey * ey + ez * ez), 1e-8f);
        float inv = 1.0f / len;
        float dx = ex * inv, dy = ey * inv, dz = ez * inv;

        const float* xr = x + (size_t)si * 32 + kg * 8;
        float4 xa = *(const float4*)xr;
        float4 xb = *(const float4*)(xr + 4);
        half8 hx;
        hx[0] = (_Float16)xa.x; hx[1] = (_Float16)xa.y;
        hx[2] = (_Float16)xa.z; hx[3] = (_Float16)xa.w;
        hx[4] = (_Float16)xb.x; hx[5] = (_Float16)xb.y;
        hx[6] = (_Float16)xb.z; hx[7] = (_Float16)xb.w;
        *(half8*)&myfeat[e16 * 40 + kg * 8] = hx;
        if (kg == 0) {
            half4v g;
            g[0] = (_Float16)dx; g[1] = (_Float16)dy;
            g[2] = (_Float16)dz; g[3] = (_Float16)len;
            *(half4v*)&myfeat[e16 * 40 + 32] = g;
            mydst[e16] = di;
        }

        // A-fragments in-lane: h_j(e16) = silu(len * W1[j])
        half8 a0, a1;
        #pragma unroll
        for (int i = 0; i < 8; ++i) {
            float z0 = len * sW1[kg * 8 + i];
            a0[i] = (_Float16)(z0 / (1.0f + __expf(-z0)));
            float z1 = len * sW1[32 + kg * 8 + i];
            a1[i] = (_Float16)(z1 / (1.0f + __expf(-z1)));
        }

        // ===== phase M+E: 4 paths x (16 MFMA + epilogue), wave-private =====
        float ms[4]  = {0.f, 0.f, 0.f, 0.f};
        float mv0[4] = {0.f, 0.f, 0.f, 0.f};
        float mv1[4] = {0.f, 0.f, 0.f, 0.f};
        float mv2[4] = {0.f, 0.f, 0.f, 0.f};

        #pragma unroll
        for (int p = 0; p < 4; ++p) {
            floatx4 acc[8];
            #pragma unroll
            for (int t = 0; t < 8; ++t) {
                half8 b0 = bwv[((p * 8 + t) * 2 + 0) * 64 + lane];
                half8 b1 = bwv[((p * 8 + t) * 2 + 1) * 64 + lane];
                floatx4 z = {0.f, 0.f, 0.f, 0.f};
                z = __builtin_amdgcn_mfma_f32_16x16x32_f16(a0, b0, z, 0, 0, 0);
                acc[t] = __builtin_amdgcn_mfma_f32_16x16x32_f16(a1, b1, z, 0, 0, 0);
            }

            #pragma unroll
            for (int r = 0; r < 4; ++r) {
                const _Float16* fb = &myfeat[(kg * 4 + r) * 40];
                if (p == 0) {                        // A: ms += xs . wA
                    half8 xs = *(const half8*)fb;
                    float s = 0.f;
                    #pragma unroll
                    for (int u = 0; u < 8; ++u) s += (float)xs[u] * acc[u][r];
                    ms[r] += s;
                } else if (p == 1) {                 // B: ms += (xv.dir) . wB
                    half8 cv0 = *(const half8*)(fb + 8);
                    half8 cv1 = *(const half8*)(fb + 16);
                    half8 cv2 = *(const half8*)(fb + 24);
                    half4v g = *(const half4v*)(fb + 32);
                    float gx = (float)g[0], gy = (float)g[1], gz = (float)g[2];
                    float dot[8];
                    #pragma unroll
                    for (int u = 0; u < 8; ++u) dot[u] = 0.f;
                    #pragma unroll
                    for (int f = 0; f < 24; ++f) {
                        const int c = f >> 3, j = f & 7, u = f / 3, i = f % 3;
                        float v = (c == 0) ? (float)cv0[j] : (c == 1) ? (float)cv1[j] : (float)cv2[j];
                        float gi = (i == 0) ? gx : (i == 1) ? gy : gz;
                        dot[u] += v * gi;
                    }
                    float s = 0.f;
                    #pragma unroll
                    for (int u = 0; u < 8; ++u) s += dot[u] * acc[u][r];
                    ms[r] += s;
                } else if (p == 2) {                 // C: mv += (xs.wC)*sqrt3*dir
                    half8 xs = *(const half8*)fb;
                    half4v g = *(const half4v*)(fb + 32);
                    float cw = 0.f;
                    #pragma unroll
                    for (int u = 0; u < 8; ++u) cw += (float)xs[u] * acc[u][r];
                    mv0[r] += cw * (float)g[0];
                    mv1[r] += cw * (float)g[1];
                    mv2[r] += cw * (float)g[2];
                } else {                             // D: mv += xv . wD
                    half8 cv0 = *(const half8*)(fb + 8);
                    half8 cv1 = *(const half8*)(fb + 16);
                    half8 cv2 = *(const half8*)(fb + 24);
                    #pragma unroll
                    for (int f = 0; f < 24; ++f) {
                        const int c = f >> 3, j = f & 7, u = f / 3, i = f % 3;
                        float v = (c == 0) ? (float)cv0[j] : (c == 1) ? (float)cv1[j] : (float)cv2[j];
                        float w = v * acc[u][r];
                        if (i == 0) mv0[r] += w;
                        else if (i == 1) mv1[r] += w;
                        else mv2[r] += w;
                    }
                }
            }
        }

        // ===== phase S: atomic scatter (no barrier) =====
        #pragma unroll
        for (int r = 0; r < 4; ++r) {
            int e = kg * 4 + r;
            if (tile * 16 + e < E) {
                float* o = out + (size_t)mydst[e] * 64;
                atomicAdd(o + e16, ms[r]);
                atomicAdd(o + 16 + e16 * 3 + 0, mv0[r]);
                atomicAdd(o + 16 + e16 * 3 + 1, mv1[r]);
                atomicAdd(o + 16 + e16 * 3 + 2, mv2[r]);
            }
        }
    }
}

__global__ __launch_bounds__(256) void node_kernel(
    float* __restrict__ out, const float* __restrict__ Ws,
    const float* __restrict__ Wns, const float* __restrict__ Wg, int N)
{
    int n = blockIdx.x * 256 + threadIdx.x;
    if (n >= N) return;
    float* row = out + (size_t)n * 64;

    float os[16], ov[48];
    #pragma unroll
    for (int q = 0; q < 4; ++q) {
        float4 v = *reinterpret_cast<const float4*>(row + q * 4);
        os[q*4+0]=v.x; os[q*4+1]=v.y; os[q*4+2]=v.z; os[q*4+3]=v.w;
    }
    #pragma unroll
    for (int q = 0; q < 12; ++q) {
        float4 v = *reinterpret_cast<const float4*>(row + 16 + q * 4);
        ov[q*4+0]=v.x; ov[q*4+1]=v.y; ov[q*4+2]=v.z; ov[q*4+3]=v.w;
    }

    float sres[16], gres[16];
    #pragma unroll
    for (int w = 0; w < 16; ++w) {
        float a = 0.f, b = 0.f;
        #pragma unroll
        for (int u = 0; u < 16; ++u) {
            float o_u = os[u];
            a += o_u * Ws[u * 16 + w];
            b += o_u * Wg[u * 16 + w];
        }
        a *= 0.25f; b *= 0.25f;
        sres[w] = a / (1.0f + __expf(-a));
        gres[w] = 1.0f / (1.0f + __expf(-b));
    }

    float gated[48];
    #pragma unroll
    for (int w = 0; w < 16; ++w) {
        float n0 = 0.f, n1 = 0.f, n2 = 0.f;
        #pragma unroll
        for (int u = 0; u < 16; ++u) {
            float wn = Wns[u * 16 + w];
            n0 += ov[u*3+0] * wn;
            n1 += ov[u*3+1] * wn;
            n2 += ov[u*3+2] * wn;
        }
        float gw = gres[w] * 0.25f;
        gated[w*3+0] = n0 * gw;
        gated[w*3+1] = n1 * gw;
        gated[w*3+2] = n2 * gw;
    }

    #pragma unroll
    for (int q = 0; q < 4; ++q) {
        float4 v = make_float4(sres[q*4+0], sres[q*4+1], sres[q*4+2], sres[q*4+3]);
        *reinterpret_cast<float4*>(row + q * 4) = v;
    }
    #pragma unroll
    for (int q = 0; q < 12; ++q) {
        float4 v = make_float4(gated[q*4+0], gated[q*4+1], gated[q*4+2], gated[q*4+3]);
        *reinterpret_cast<float4*>(row + 16 + q * 4) = v;
    }
}

extern "C" void kernel_launch(void* const* d_in, const int* in_sizes, int n_in,
                              void* d_out, int out_size, void* d_ws, size_t ws_size,
                              hipStream_t stream) {
    const float* x   = (const float*)d_in[0];
    const float* pos = (const float*)d_in[1];
    const int*   ei  = (const int*)d_in[2];
    const float* W1  = (const float*)d_in[3];
    const float* W2  = (const float*)d_in[4];
    const float* Ws  = (const float*)d_in[5];
    const float* Wns = (const float*)d_in[6];
    const float* Wg  = (const float*)d_in[7];

    int N = in_sizes[0] / 32;
    int E = in_sizes[2] / 2;
    int ntiles = (E + 15) / 16;
    float* out = (float*)d_out;
    _Float16* bw = (_Float16*)d_ws;

    (void)hipMemsetAsync(out, 0, (size_t)N * 64 * sizeof(float), stream);
    prep_w2<<<128, 256, 0, stream>>>(W2, bw);
    int nblk = 512;
    edge_kernel<<<nblk, 512, 0, stream>>>(x, pos, ei, W1, bw, out, E, ntiles);
    node_kernel<<<(N + 255) / 256, 256, 0, stream>>>(out, Ws, Wns, Wg, N);
}

// Round 13
// 108.822 us; speedup vs baseline: 5.5322x; 5.5322x over previous
//
#include <hip/hip_runtime.h>
#include <math.h>

typedef _Float16 half8 __attribute__((ext_vector_type(8)));
typedef float floatx4 __attribute__((ext_vector_type(4)));

#define SQ3 1.7320508075688772f

// LDS-only barrier: waits LDS ops, does NOT drain vmcnt (global loads/atomics
// stay in flight across the barrier). sched_barrier(0) fences code motion.
__device__ __forceinline__ void bar_lds() {
    __builtin_amdgcn_sched_barrier(0);
    asm volatile("s_waitcnt lgkmcnt(0)\n\ts_barrier" ::: "memory");
    __builtin_amdgcn_sched_barrier(0);
}

// bw layout: [path(4)][t(8)][s(2)][lane(64)][elem(8)] _Float16  (32768 = 64 KiB)
// bw value = W2[k][col] * scale, k = s*32 + (lane>>4)*8 + elem,
// col = path*128 + t*16 + (lane&15), scale = 1/32 (sqrt3 folded into path C)
__global__ __launch_bounds__(256) void prep_w2(const float* __restrict__ W2,
                                               _Float16* __restrict__ bw) {
    int t = blockIdx.x * 256 + threadIdx.x;
    if (t >= 32768) return;
    int i    = t & 7;
    int l    = (t >> 3) & 63;
    int s    = (t >> 9) & 1;
    int tt   = (t >> 10) & 7;
    int path = t >> 13;
    int k   = s * 32 + (l >> 4) * 8 + i;
    int col = path * 128 + tt * 16 + (l & 15);
    float scale = 0.03125f * (path == 2 ? SQ3 : 1.0f);
    bw[t] = (_Float16)(W2[k * 512 + col] * scale);
}

struct Pref {
    float4 xa;
    float psx, psy, psz, pdx, pdy, pdz;
    int di;
};

__device__ __forceinline__ Pref issue_loads(int tile, int E,
        const int* __restrict__ ei, const float* __restrict__ x,
        const float* __restrict__ pos, int tid) {
    Pref p;
    int el = tid >> 3, q = tid & 7;
    int eg = tile * 64 + el;
    int ec = (eg < E) ? eg : (E - 1);
    int si = ei[ec];
    p.di = ei[E + ec];
    p.xa = *reinterpret_cast<const float4*>(x + (size_t)si * 32 + q * 4);
    const float* ps = pos + (size_t)si * 3;
    const float* pd = pos + (size_t)p.di * 3;
    p.psx = ps[0]; p.psy = ps[1]; p.psz = ps[2];
    p.pdx = pd[0]; p.pdy = pd[1]; p.pdz = pd[2];
    return p;
}

// 512 threads = 8 waves = (path 0..3) x (u-half 0..1)
__global__ __launch_bounds__(512, 4) void edge_kernel(
    const float* __restrict__ x, const float* __restrict__ pos,
    const int* __restrict__ ei, const float* __restrict__ W1,
    const _Float16* __restrict__ bw, float* __restrict__ out,
    int E, int ntiles)
{
    __shared__ float sW1[64];
    __shared__ __align__(16) float4 s_geo[64];
    __shared__ int s_dst[2][64];
    __shared__ __align__(16) float s_xs[64][12];
    __shared__ __align__(16) float s_xvp[3][64][12];
    __shared__ __align__(16) _Float16 s_hA[4][2][64][8];
    __shared__ __align__(16) _Float16 s_part[4][64][66];

    const int tid  = threadIdx.x;
    const int wave = tid >> 6;
    const int path = wave >> 1;    // 0..3 == A,B,C,D
    const int th   = wave & 1;     // u-half: u in [th*4, th*4+4)
    const int lane = tid & 63;
    const int ub   = th * 4;

    if (tid < 64) sW1[tid] = W1[tid];

    // register-resident B fragments: this wave's path + u-half (8 frags = 32 VGPR)
    half8 bfrag[4][2];
    {
        const half8* bsrc = (const half8*)bw;
        #pragma unroll
        for (int tt = 0; tt < 4; ++tt)
            #pragma unroll
            for (int s = 0; s < 2; ++s)
                bfrag[tt][s] = bsrc[(size_t)path * 1024 + ((ub + tt) * 2 + s) * 64 + lane];
    }

    int tile = blockIdx.x;
    if (tile >= ntiles) return;
    Pref p = issue_loads(tile, E, ei, x, pos, tid);
    bar_lds();   // sW1 visible before first stage A

    int buf = 0;
    for (; tile < ntiles; tile += gridDim.x) {
        // ===== stage A: prefetched regs -> LDS (geo, features, h frags) =====
        {
            int el = tid >> 3, q = tid & 7;
            float ex = p.pdx - p.psx;
            float ey = p.pdy - p.psy;
            float ez = p.pdz - p.psz;
            float len = fmaxf(sqrtf(ex * ex + ey * ey + ez * ez), 1e-8f);
            float inv = 1.0f / len;
            if (q == 0) {
                s_geo[el] = make_float4(ex * inv, ey * inv, ez * inv, len);
                s_dst[buf][el] = p.di;
            }
            if (q < 2) {
                *(float4*)&s_xs[el][q * 4] = p.xa;
            } else {
                float vals[4] = {p.xa.x, p.xa.y, p.xa.z, p.xa.w};
                #pragma unroll
                for (int j = 0; j < 4; ++j) {
                    int flat = (q - 2) * 4 + j;      // 0..23
                    int u  = (flat * 11) >> 5;       // flat/3
                    int ii = flat - 3 * u;
                    s_xvp[ii][el][u] = vals[j];
                }
            }
            int s  = q >> 2, kg = q & 3;
            int sub = el >> 4;
            int l   = kg * 16 + (el & 15);
            half8 ha;
            #pragma unroll
            for (int i = 0; i < 8; ++i) {
                float z = len * sW1[s * 32 + kg * 8 + i];
                ha[i] = (_Float16)(z / (1.0f + __expf(-z)));
            }
            *(half8*)&s_hA[sub][s][l][0] = ha;
        }
        bar_lds();   // bar1: tile's LDS ready (vmem stays in flight)

        // ---- prefetch next tile (loads fly during stage B and beyond) ----
        int nt = tile + gridDim.x;
        Pref pn;
        if (nt < ntiles) pn = issue_loads(nt, E, ei, x, pos, tid);

        // ===== stage B: 4 subtiles x 8 MFMA per wave + half-epilogue =====
        const int wp  = lane & 15;
        const int er0 = (lane >> 4) * 4;
        #pragma unroll
        for (int sub = 0; sub < 4; ++sub) {
            half8 a0 = *(const half8*)&s_hA[sub][0][lane][0];
            half8 a1 = *(const half8*)&s_hA[sub][1][lane][0];
            floatx4 acc[4];
            #pragma unroll
            for (int tt = 0; tt < 4; ++tt) {
                floatx4 z = {0.f, 0.f, 0.f, 0.f};
                z = __builtin_amdgcn_mfma_f32_16x16x32_f16(a0, bfrag[tt][0], z, 0, 0, 0);
                acc[tt] = __builtin_amdgcn_mfma_f32_16x16x32_f16(a1, bfrag[tt][1], z, 0, 0, 0);
            }

            if (path == 0) {                 // A: ms(half) = xs[ub..ub+3] . wA
                #pragma unroll
                for (int r = 0; r < 4; ++r) {
                    int e = sub * 16 + er0 + r;
                    float4 x0 = *(const float4*)&s_xs[e][ub];
                    float m = x0.x*acc[0][r] + x0.y*acc[1][r] + x0.z*acc[2][r] + x0.w*acc[3][r];
                    s_part[th][e][wp] = (_Float16)m;
                }
            } else if (path == 1) {          // B: ms(half) = (xv.dir)[ub..] . wB
                #pragma unroll
                for (int r = 0; r < 4; ++r) {
                    int e = sub * 16 + er0 + r;
                    float4 g = s_geo[e];
                    float4 v0 = *(const float4*)&s_xvp[0][e][ub];
                    float4 v1 = *(const float4*)&s_xvp[1][e][ub];
                    float4 v2 = *(const float4*)&s_xvp[2][e][ub];
                    float d0 = v0.x*acc[0][r] + v0.y*acc[1][r] + v0.z*acc[2][r] + v0.w*acc[3][r];
                    float d1 = v1.x*acc[0][r] + v1.y*acc[1][r] + v1.z*acc[2][r] + v1.w*acc[3][r];
                    float d2 = v2.x*acc[0][r] + v2.y*acc[1][r] + v2.z*acc[2][r] + v2.w*acc[3][r];
                    s_part[2 + th][e][wp] = (_Float16)(g.x*d0 + g.y*d1 + g.z*d2);
                }
            } else if (path == 2) {          // C: mv(half) = (xs.wC) * sqrt3*dir
                #pragma unroll
                for (int r = 0; r < 4; ++r) {
                    int e = sub * 16 + er0 + r;
                    float4 x0 = *(const float4*)&s_xs[e][ub];
                    float4 g = s_geo[e];
                    float cw = x0.x*acc[0][r] + x0.y*acc[1][r] + x0.z*acc[2][r] + x0.w*acc[3][r];
                    s_part[th][e][16 + wp * 3 + 0] = (_Float16)(cw * g.x);
                    s_part[th][e][16 + wp * 3 + 1] = (_Float16)(cw * g.y);
                    s_part[th][e][16 + wp * 3 + 2] = (_Float16)(cw * g.z);
                }
            } else {                         // D: mv(half) = xv[ub..] . wD
                #pragma unroll
                for (int r = 0; r < 4; ++r) {
                    int e = sub * 16 + er0 + r;
                    #pragma unroll
                    for (int i = 0; i < 3; ++i) {
                        float4 v0 = *(const float4*)&s_xvp[i][e][ub];
                        float mi = v0.x*acc[0][r] + v0.y*acc[1][r] + v0.z*acc[2][r] + v0.w*acc[3][r];
                        s_part[2 + th][e][16 + wp * 3 + i] = (_Float16)mi;
                    }
                }
            }
        }
        bar_lds();   // bar2: partials ready (prefetch + atomics stay in flight)

        // ===== stage C: sum 4 partials, coalesced atomic scatter =====
        {
            int c = tid & 63;
            int g = tid >> 6;
            #pragma unroll
            for (int k = 0; k < 8; ++k) {
                int e  = g * 8 + k;
                int eg = tile * 64 + e;
                if (eg < E) {
                    float v = (float)s_part[0][e][c] + (float)s_part[1][e][c]
                            + (float)s_part[2][e][c] + (float)s_part[3][e][c];
                    atomicAdd(out + (size_t)s_dst[buf][e] * 64 + c, v);
                }
            }
        }
        p = pn;
        buf ^= 1;
    }
}

__global__ __launch_bounds__(256) void node_kernel(
    float* __restrict__ out, const float* __restrict__ Ws,
    const float* __restrict__ Wns, const float* __restrict__ Wg, int N)
{
    int n = blockIdx.x * 256 + threadIdx.x;
    if (n >= N) return;
    float* row = out + (size_t)n * 64;

    float os[16], ov[48];
    #pragma unroll
    for (int q = 0; q < 4; ++q) {
        float4 v = *reinterpret_cast<const float4*>(row + q * 4);
        os[q*4+0]=v.x; os[q*4+1]=v.y; os[q*4+2]=v.z; os[q*4+3]=v.w;
    }
    #pragma unroll
    for (int q = 0; q < 12; ++q) {
        float4 v = *reinterpret_cast<const float4*>(row + 16 + q * 4);
        ov[q*4+0]=v.x; ov[q*4+1]=v.y; ov[q*4+2]=v.z; ov[q*4+3]=v.w;
    }

    float sres[16], gres[16];
    #pragma unroll
    for (int w = 0; w < 16; ++w) {
        float a = 0.f, b = 0.f;
        #pragma unroll
        for (int u = 0; u < 16; ++u) {
            float o_u = os[u];
            a += o_u * Ws[u * 16 + w];
            b += o_u * Wg[u * 16 + w];
        }
        a *= 0.25f; b *= 0.25f;
        sres[w] = a / (1.0f + __expf(-a));
        gres[w] = 1.0f / (1.0f + __expf(-b));
    }

    float gated[48];
    #pragma unroll
    for (int w = 0; w < 16; ++w) {
        float n0 = 0.f, n1 = 0.f, n2 = 0.f;
        #pragma unroll
        for (int u = 0; u < 16; ++u) {
            float wn = Wns[u * 16 + w];
            n0 += ov[u*3+0] * wn;
            n1 += ov[u*3+1] * wn;
            n2 += ov[u*3+2] * wn;
        }
        float gw = gres[w] * 0.25f;
        gated[w*3+0] = n0 * gw;
        gated[w*3+1] = n1 * gw;
        gated[w*3+2] = n2 * gw;
    }

    #pragma unroll
    for (int q = 0; q < 4; ++q) {
        float4 v = make_float4(sres[q*4+0], sres[q*4+1], sres[q*4+2], sres[q*4+3]);
        *reinterpret_cast<float4*>(row + q * 4) = v;
    }
    #pragma unroll
    for (int q = 0; q < 12; ++q) {
        float4 v = make_float4(gated[q*4+0], gated[q*4+1], gated[q*4+2], gated[q*4+3]);
        *reinterpret_cast<float4*>(row + 16 + q * 4) = v;
    }
}

extern "C" void kernel_launch(void* const* d_in, const int* in_sizes, int n_in,
                              void* d_out, int out_size, void* d_ws, size_t ws_size,
                              hipStream_t stream) {
    const float* x   = (const float*)d_in[0];
    const float* pos = (const float*)d_in[1];
    const int*   ei  = (const int*)d_in[2];
    const float* W1  = (const float*)d_in[3];
    const float* W2  = (const float*)d_in[4];
    const float* Ws  = (const float*)d_in[5];
    const float* Wns = (const float*)d_in[6];
    const float* Wg  = (const float*)d_in[7];

    int N = in_sizes[0] / 32;
    int E = in_sizes[2] / 2;
    int ntiles = (E + 63) / 64;
    float* out = (float*)d_out;
    _Float16* bw = (_Float16*)d_ws;

    (void)hipMemsetAsync(out, 0, (size_t)N * 64 * sizeof(float), stream);
    prep_w2<<<128, 256, 0, stream>>>(W2, bw);
    int nblk = ntiles < 512 ? ntiles : 512;
    edge_kernel<<<nblk, 512, 0, stream>>>(x, pos, ei, W1, bw, out, E, ntiles);
    node_kernel<<<(N + 255) / 256, 256, 0, stream>>>(out, Ws, Wns, Wg, N);
}